// Round 1
// baseline (601.906 us; speedup 1.0000x reference)
//
#include <hip/hip_runtime.h>
#include <hip/hip_bf16.h>
#include <math.h>

#define N_TOK 4096
#define DIM   1024
#define NEXP  8
#define IDIM  2048
#define TWOI  4096
#define CAP   1280

using short8  = __attribute__((ext_vector_type(8))) short;
using floatx4 = __attribute__((ext_vector_type(4))) float;

__device__ __forceinline__ unsigned short f2b(float f) {
  __hip_bfloat16 h = __float2bfloat16(f);
  return *reinterpret_cast<unsigned short*>(&h);
}

// ---------------- conversion kernels ----------------

__global__ __launch_bounds__(256) void conv_x_kernel(const float* __restrict__ x,
                                                     unsigned short* __restrict__ xb) {
  int i = (blockIdx.x * 256 + threadIdx.x) * 4;
  float4 v = *reinterpret_cast<const float4*>(x + i);
  ushort4 o;
  o.x = f2b(v.x); o.y = f2b(v.y); o.z = f2b(v.z); o.w = f2b(v.w);
  *reinterpret_cast<ushort4*>(xb + i) = o;
}

// src: [E][R][C] fp32  ->  dst: [E][C][R] bf16
__global__ __launch_bounds__(256) void transpose_kernel(const float* __restrict__ src,
                                                        unsigned short* __restrict__ dst,
                                                        int R, int C) {
  __shared__ float tile[32][33];
  int e  = blockIdx.z;
  int c0 = blockIdx.x * 32, r0 = blockIdx.y * 32;
  int tx = threadIdx.x & 31, ty = threadIdx.x >> 5;
  const float* s = src + (size_t)e * R * C;
  unsigned short* d = dst + (size_t)e * R * C;
#pragma unroll
  for (int i = 0; i < 4; i++) {
    int r = ty + i * 8;
    tile[r][tx] = s[(size_t)(r0 + r) * C + c0 + tx];
  }
  __syncthreads();
#pragma unroll
  for (int i = 0; i < 4; i++) {
    int c = ty + i * 8;
    d[(size_t)(c0 + c) * R + r0 + tx] = f2b(tile[tx][c]);
  }
}

// ---------------- router ----------------
// one wave per token; fp64 accumulation so top-2 ordering matches numpy ref
__global__ __launch_bounds__(256) void router_kernel(const float* __restrict__ x,
                                                     const float* __restrict__ Wg,
                                                     int* __restrict__ top_i,
                                                     float* __restrict__ gates) {
  __shared__ float wg[NEXP * DIM];
  int tid = threadIdx.x;
  for (int i = tid * 4; i < NEXP * DIM; i += 256 * 4) {
    *reinterpret_cast<float4*>(wg + i) = *reinterpret_cast<const float4*>(Wg + i);
  }
  __syncthreads();
  int wave = tid >> 6, lane = tid & 63;
  int t = blockIdx.x * 4 + wave;
  const float* xr = x + (size_t)t * DIM;
  double acc[NEXP];
#pragma unroll
  for (int e = 0; e < NEXP; e++) acc[e] = 0.0;
  for (int i = lane; i < DIM; i += 64) {
    double xv = (double)xr[i];
#pragma unroll
    for (int e = 0; e < NEXP; e++) acc[e] += xv * (double)wg[e * DIM + i];
  }
#pragma unroll
  for (int e = 0; e < NEXP; e++) {
#pragma unroll
    for (int m = 1; m < 64; m <<= 1) acc[e] += __shfl_xor(acc[e], m, 64);
  }
  if (lane == 0) {
    int i0 = 0; double v0 = acc[0];
    for (int e = 1; e < NEXP; e++) { if (acc[e] > v0) { v0 = acc[e]; i0 = e; } }
    int i1 = -1; double v1 = -1e300;
    for (int e = 0; e < NEXP; e++) { if (e != i0 && acc[e] > v1) { v1 = acc[e]; i1 = e; } }
    double e1 = exp(v1 - v0);
    float g0 = (float)(1.0 / (1.0 + e1));
    float g1 = (float)(e1 / (1.0 + e1));
    top_i[t * 2] = i0; top_i[t * 2 + 1] = i1;
    gates[t * 2] = g0; gates[t * 2 + 1] = g1;
  }
}

// ---------------- capacity scan (deterministic, token-major slot order) ----------------
__global__ __launch_bounds__(256) void scan_kernel(const int* __restrict__ top_i,
                                                   const float* __restrict__ gates,
                                                   int* __restrict__ slot_pos,
                                                   float* __restrict__ keepg,
                                                   int* __restrict__ rowtok,
                                                   int* __restrict__ cnt) {
  __shared__ int hist[NEXP][256];
  int t = threadIdx.x;
  int s0 = t * 32;
  int eloc[32];
  int c[NEXP];
#pragma unroll
  for (int e = 0; e < NEXP; e++) c[e] = 0;
#pragma unroll
  for (int j = 0; j < 32; j++) { int e = top_i[s0 + j]; eloc[j] = e; c[e]++; }
#pragma unroll
  for (int e = 0; e < NEXP; e++) hist[e][t] = c[e];
  __syncthreads();
  for (int step = 1; step < 256; step <<= 1) {
    int tmp[NEXP];
#pragma unroll
    for (int e = 0; e < NEXP; e++) tmp[e] = (t >= step) ? hist[e][t - step] : 0;
    __syncthreads();
#pragma unroll
    for (int e = 0; e < NEXP; e++) hist[e][t] += tmp[e];
    __syncthreads();
  }
  int base[NEXP];
#pragma unroll
  for (int e = 0; e < NEXP; e++) base[e] = hist[e][t] - c[e];
  if (t < NEXP) {
    int tot = hist[t][255];
    cnt[t] = tot < CAP ? tot : CAP;
  }
#pragma unroll
  for (int j = 0; j < 32; j++) {
    int s = s0 + j;
    int e = eloc[j];
    int pos = base[e]++;
    bool keep = pos < CAP;
    slot_pos[s] = keep ? pos : 0;
    keepg[s] = keep ? gates[s] : 0.0f;
    if (keep) rowtok[e * CAP + pos] = s >> 1;
  }
}

// ---------------- GEMM1 + GLU: H[e][m][i] = gelu(X@W1_inp) * (X@W1_gate) ----------------
// xb: [N_TOK][DIM] bf16, w1t: [E][TWOI][DIM] bf16 (K-major), H: [E][CAP][IDIM] bf16
__global__ __launch_bounds__(256) void gemm1_kernel(const unsigned short* __restrict__ xb,
                                                    const unsigned short* __restrict__ w1t,
                                                    const int* __restrict__ rowtok,
                                                    const int* __restrict__ cnt,
                                                    unsigned short* __restrict__ H) {
  int e  = blockIdx.z;
  int m0 = blockIdx.y * 128;
  int i0 = blockIdx.x * 128;
  int cnte = cnt[e];
  if (m0 >= cnte) return;

  __shared__ __align__(16) unsigned short As[128 * 40];
  __shared__ __align__(16) unsigned short Bi[128 * 40];
  __shared__ __align__(16) unsigned short Bg[128 * 40];

  int tid = threadIdx.x;
  int ra = tid >> 2;
  int kc = (tid & 3) * 8;

  int ma = m0 + ra, mb = m0 + ra + 64;
  int toka = (ma < cnte) ? rowtok[e * CAP + ma] : 0;
  int tokb = (mb < cnte) ? rowtok[e * CAP + mb] : 0;

  const unsigned short* w1e = w1t + (size_t)e * TWOI * DIM;
  const unsigned short* arow0 = xb + (size_t)toka * DIM;
  const unsigned short* arow1 = xb + (size_t)tokb * DIM;
  const unsigned short* browi0 = w1e + (size_t)(i0 + ra) * DIM;
  const unsigned short* browi1 = w1e + (size_t)(i0 + ra + 64) * DIM;
  const unsigned short* browg0 = w1e + (size_t)(i0 + ra + IDIM) * DIM;
  const unsigned short* browg1 = w1e + (size_t)(i0 + ra + 64 + IDIM) * DIM;

  int lane = tid & 63;
  int wave = tid >> 6;
  int lane16 = lane & 15;
  int quad = lane >> 4;
  int wm = (wave & 1) * 64;
  int wn = (wave >> 1) * 64;

  floatx4 acc_i[4][4], acc_g[4][4];
#pragma unroll
  for (int i = 0; i < 4; i++)
#pragma unroll
    for (int j = 0; j < 4; j++) {
      acc_i[i][j] = (floatx4){0.f, 0.f, 0.f, 0.f};
      acc_g[i][j] = (floatx4){0.f, 0.f, 0.f, 0.f};
    }

  for (int k0 = 0; k0 < DIM; k0 += 32) {
    __syncthreads();
    *(short8*)&As[ra * 40 + kc]        = *(const short8*)&arow0[k0 + kc];
    *(short8*)&As[(ra + 64) * 40 + kc] = *(const short8*)&arow1[k0 + kc];
    *(short8*)&Bi[ra * 40 + kc]        = *(const short8*)&browi0[k0 + kc];
    *(short8*)&Bi[(ra + 64) * 40 + kc] = *(const short8*)&browi1[k0 + kc];
    *(short8*)&Bg[ra * 40 + kc]        = *(const short8*)&browg0[k0 + kc];
    *(short8*)&Bg[(ra + 64) * 40 + kc] = *(const short8*)&browg1[k0 + kc];
    __syncthreads();

    short8 a[4], bi[4], bg[4];
#pragma unroll
    for (int i = 0; i < 4; i++)
      a[i] = *(const short8*)&As[(wm + i * 16 + lane16) * 40 + quad * 8];
#pragma unroll
    for (int j = 0; j < 4; j++) {
      bi[j] = *(const short8*)&Bi[(wn + j * 16 + lane16) * 40 + quad * 8];
      bg[j] = *(const short8*)&Bg[(wn + j * 16 + lane16) * 40 + quad * 8];
    }
#pragma unroll
    for (int i = 0; i < 4; i++)
#pragma unroll
      for (int j = 0; j < 4; j++) {
        acc_i[i][j] = __builtin_amdgcn_mfma_f32_16x16x32_bf16(a[i], bi[j], acc_i[i][j], 0, 0, 0);
        acc_g[i][j] = __builtin_amdgcn_mfma_f32_16x16x32_bf16(a[i], bg[j], acc_g[i][j], 0, 0, 0);
      }
  }

  unsigned short* He = H + (size_t)e * CAP * IDIM;
#pragma unroll
  for (int i = 0; i < 4; i++) {
#pragma unroll
    for (int r = 0; r < 4; r++) {
      int m = m0 + wm + i * 16 + quad * 4 + r;
#pragma unroll
      for (int j = 0; j < 4; j++) {
        int n = i0 + wn + j * 16 + lane16;
        float vi = acc_i[i][j][r];
        float vg = acc_g[i][j][r];
        float h = 0.5f * vi * (1.0f + erff(vi * 0.70710678118654752f)) * vg;
        He[(size_t)m * IDIM + n] = f2b(h);
      }
    }
  }
}

// ---------------- GEMM2: expout[e][m][n] = H[e] @ W2[e] ----------------
// H: [E][CAP][IDIM] bf16, w2t: [E][DIM][IDIM] bf16 (K-major), expout: [E][CAP][DIM] fp32
__global__ __launch_bounds__(256) void gemm2_kernel(const unsigned short* __restrict__ H,
                                                    const unsigned short* __restrict__ w2t,
                                                    const int* __restrict__ cnt,
                                                    float* __restrict__ expout) {
  int e  = blockIdx.z;
  int m0 = blockIdx.y * 128;
  int n0 = blockIdx.x * 128;
  int cnte = cnt[e];
  if (m0 >= cnte) return;

  __shared__ __align__(16) unsigned short As[128 * 40];
  __shared__ __align__(16) unsigned short Bs[128 * 40];

  int tid = threadIdx.x;
  int ra = tid >> 2;
  int kc = (tid & 3) * 8;

  const unsigned short* He  = H + (size_t)e * CAP * IDIM;
  const unsigned short* w2e = w2t + (size_t)e * DIM * IDIM;
  const unsigned short* arow0 = He + (size_t)(m0 + ra) * IDIM;
  const unsigned short* arow1 = He + (size_t)(m0 + ra + 64) * IDIM;
  const unsigned short* brow0 = w2e + (size_t)(n0 + ra) * IDIM;
  const unsigned short* brow1 = w2e + (size_t)(n0 + ra + 64) * IDIM;

  int lane = tid & 63;
  int wave = tid >> 6;
  int lane16 = lane & 15;
  int quad = lane >> 4;
  int wm = (wave & 1) * 64;
  int wn = (wave >> 1) * 64;

  floatx4 acc[4][4];
#pragma unroll
  for (int i = 0; i < 4; i++)
#pragma unroll
    for (int j = 0; j < 4; j++) acc[i][j] = (floatx4){0.f, 0.f, 0.f, 0.f};

  for (int k0 = 0; k0 < IDIM; k0 += 32) {
    __syncthreads();
    *(short8*)&As[ra * 40 + kc]        = *(const short8*)&arow0[k0 + kc];
    *(short8*)&As[(ra + 64) * 40 + kc] = *(const short8*)&arow1[k0 + kc];
    *(short8*)&Bs[ra * 40 + kc]        = *(const short8*)&brow0[k0 + kc];
    *(short8*)&Bs[(ra + 64) * 40 + kc] = *(const short8*)&brow1[k0 + kc];
    __syncthreads();

    short8 a[4], b[4];
#pragma unroll
    for (int i = 0; i < 4; i++)
      a[i] = *(const short8*)&As[(wm + i * 16 + lane16) * 40 + quad * 8];
#pragma unroll
    for (int j = 0; j < 4; j++)
      b[j] = *(const short8*)&Bs[(wn + j * 16 + lane16) * 40 + quad * 8];
#pragma unroll
    for (int i = 0; i < 4; i++)
#pragma unroll
      for (int j = 0; j < 4; j++)
        acc[i][j] = __builtin_amdgcn_mfma_f32_16x16x32_bf16(a[i], b[j], acc[i][j], 0, 0, 0);
  }

  float* oute = expout + (size_t)e * CAP * DIM;
#pragma unroll
  for (int i = 0; i < 4; i++) {
#pragma unroll
    for (int r = 0; r < 4; r++) {
      int m = m0 + wm + i * 16 + quad * 4 + r;
#pragma unroll
      for (int j = 0; j < 4; j++) {
        int n = n0 + wn + j * 16 + lane16;
        oute[(size_t)m * DIM + n] = acc[i][j][r];
      }
    }
  }
}

// ---------------- combine ----------------
__global__ __launch_bounds__(256) void combine_kernel(const int* __restrict__ top_i,
                                                      const int* __restrict__ slot_pos,
                                                      const float* __restrict__ keepg,
                                                      const float* __restrict__ expout,
                                                      float* __restrict__ out) {
  int t = blockIdx.x;
  int tid = threadIdx.x;
  int e0 = top_i[t * 2], e1 = top_i[t * 2 + 1];
  int p0 = slot_pos[t * 2], p1 = slot_pos[t * 2 + 1];
  float g0 = keepg[t * 2], g1 = keepg[t * 2 + 1];
  const float4* r0 = reinterpret_cast<const float4*>(expout + ((size_t)e0 * CAP + p0) * DIM);
  const float4* r1 = reinterpret_cast<const float4*>(expout + ((size_t)e1 * CAP + p1) * DIM);
  float4 a = r0[tid], b = r1[tid];
  float4 o;
  o.x = g0 * a.x + g1 * b.x;
  o.y = g0 * a.y + g1 * b.y;
  o.z = g0 * a.z + g1 * b.z;
  o.w = g0 * a.w + g1 * b.w;
  reinterpret_cast<float4*>(out + (size_t)t * DIM)[tid] = o;
}

// ---------------- launch ----------------
extern "C" void kernel_launch(void* const* d_in, const int* in_sizes, int n_in,
                              void* d_out, int out_size, void* d_ws, size_t ws_size,
                              hipStream_t stream) {
  const float* x  = (const float*)d_in[0];
  const float* Wg = (const float*)d_in[1];
  const float* W1 = (const float*)d_in[2];
  const float* W2 = (const float*)d_in[3];
  float* out = (float*)d_out;

  char* ws = (char*)d_ws;
  size_t off = 0;
  auto alloc = [&](size_t bytes) -> void* {
    void* p = ws + off;
    off = (off + bytes + 255) & ~(size_t)255;
    return p;
  };
  int*   top_i    = (int*)alloc((size_t)N_TOK * 2 * sizeof(int));
  float* gates    = (float*)alloc((size_t)N_TOK * 2 * sizeof(float));
  int*   slot_pos = (int*)alloc((size_t)N_TOK * 2 * sizeof(int));
  float* keepg    = (float*)alloc((size_t)N_TOK * 2 * sizeof(float));
  int*   rowtok   = (int*)alloc((size_t)NEXP * CAP * sizeof(int));
  int*   cnt      = (int*)alloc((size_t)NEXP * sizeof(int));
  unsigned short* xb  = (unsigned short*)alloc((size_t)N_TOK * DIM * 2);
  unsigned short* w1t = (unsigned short*)alloc((size_t)NEXP * TWOI * DIM * 2);
  unsigned short* w2t = (unsigned short*)alloc((size_t)NEXP * DIM * IDIM * 2);
  unsigned short* Hb  = (unsigned short*)alloc((size_t)NEXP * CAP * IDIM * 2);
  float* expout = (float*)alloc((size_t)NEXP * CAP * DIM * sizeof(float));
  if (off > ws_size) return;  // workspace too small; avoid OOB writes

  hipLaunchKernelGGL(conv_x_kernel, dim3(N_TOK * DIM / 1024), dim3(256), 0, stream, x, xb);
  hipLaunchKernelGGL(transpose_kernel, dim3(TWOI / 32, DIM / 32, NEXP), dim3(256), 0, stream,
                     W1, w1t, DIM, TWOI);
  hipLaunchKernelGGL(transpose_kernel, dim3(DIM / 32, IDIM / 32, NEXP), dim3(256), 0, stream,
                     W2, w2t, IDIM, DIM);
  hipLaunchKernelGGL(router_kernel, dim3(N_TOK / 4), dim3(256), 0, stream, x, Wg, top_i, gates);
  hipLaunchKernelGGL(scan_kernel, dim3(1), dim3(256), 0, stream,
                     top_i, gates, slot_pos, keepg, rowtok, cnt);
  hipLaunchKernelGGL(gemm1_kernel, dim3(IDIM / 128, CAP / 128, NEXP), dim3(256), 0, stream,
                     xb, w1t, rowtok, cnt, Hb);
  hipLaunchKernelGGL(gemm2_kernel, dim3(DIM / 128, CAP / 128, NEXP), dim3(256), 0, stream,
                     Hb, w2t, cnt, expout);
  hipLaunchKernelGGL(combine_kernel, dim3(N_TOK), dim3(256), 0, stream,
                     top_i, slot_pos, keepg, expout, out);
}

// Round 2
// 539.696 us; speedup vs baseline: 1.1153x; 1.1153x over previous
//
#include <hip/hip_runtime.h>
#include <hip/hip_bf16.h>
#include <math.h>

#define N_TOK 4096
#define DIM   1024
#define NEXP  8
#define IDIM  2048
#define TWOI  4096
#define CAP   1280

using short8  = __attribute__((ext_vector_type(8))) short;
using floatx4 = __attribute__((ext_vector_type(4))) float;

__device__ __forceinline__ unsigned short f2b(float f) {
  __hip_bfloat16 h = __float2bfloat16(f);
  return *reinterpret_cast<unsigned short*>(&h);
}

// async global->LDS, 16B per lane. LDS dst = wave-uniform base + lane*16.
__device__ __forceinline__ void async16(const unsigned short* g, unsigned short* l) {
  __builtin_amdgcn_global_load_lds(
      (const __attribute__((address_space(1))) unsigned int*)g,
      (__attribute__((address_space(3))) unsigned int*)l,
      16, 0, 0);
}

// ---------------- conversion kernels ----------------

__global__ __launch_bounds__(256) void conv_x_kernel(const float* __restrict__ x,
                                                     unsigned short* __restrict__ xb) {
  int i = (blockIdx.x * 256 + threadIdx.x) * 4;
  float4 v = *reinterpret_cast<const float4*>(x + i);
  ushort4 o;
  o.x = f2b(v.x); o.y = f2b(v.y); o.z = f2b(v.z); o.w = f2b(v.w);
  *reinterpret_cast<ushort4*>(xb + i) = o;
}

// src: [E][R][C] fp32  ->  dst: [E][C][R] bf16
__global__ __launch_bounds__(256) void transpose_kernel(const float* __restrict__ src,
                                                        unsigned short* __restrict__ dst,
                                                        int R, int C) {
  __shared__ float tile[32][33];
  int e  = blockIdx.z;
  int c0 = blockIdx.x * 32, r0 = blockIdx.y * 32;
  int tx = threadIdx.x & 31, ty = threadIdx.x >> 5;
  const float* s = src + (size_t)e * R * C;
  unsigned short* d = dst + (size_t)e * R * C;
#pragma unroll
  for (int i = 0; i < 4; i++) {
    int r = ty + i * 8;
    tile[r][tx] = s[(size_t)(r0 + r) * C + c0 + tx];
  }
  __syncthreads();
#pragma unroll
  for (int i = 0; i < 4; i++) {
    int c = ty + i * 8;
    d[(size_t)(c0 + c) * R + r0 + tx] = f2b(tile[tx][c]);
  }
}

// ---------------- router ----------------
__global__ __launch_bounds__(256) void router_kernel(const float* __restrict__ x,
                                                     const float* __restrict__ Wg,
                                                     int* __restrict__ top_i,
                                                     float* __restrict__ gates) {
  __shared__ float wg[NEXP * DIM];
  int tid = threadIdx.x;
  for (int i = tid * 4; i < NEXP * DIM; i += 256 * 4) {
    *reinterpret_cast<float4*>(wg + i) = *reinterpret_cast<const float4*>(Wg + i);
  }
  __syncthreads();
  int wave = tid >> 6, lane = tid & 63;
  int t = blockIdx.x * 4 + wave;
  const float* xr = x + (size_t)t * DIM;
  double acc[NEXP];
#pragma unroll
  for (int e = 0; e < NEXP; e++) acc[e] = 0.0;
  for (int i = lane; i < DIM; i += 64) {
    double xv = (double)xr[i];
#pragma unroll
    for (int e = 0; e < NEXP; e++) acc[e] += xv * (double)wg[e * DIM + i];
  }
#pragma unroll
  for (int e = 0; e < NEXP; e++) {
#pragma unroll
    for (int m = 1; m < 64; m <<= 1) acc[e] += __shfl_xor(acc[e], m, 64);
  }
  if (lane == 0) {
    int i0 = 0; double v0 = acc[0];
    for (int e = 1; e < NEXP; e++) { if (acc[e] > v0) { v0 = acc[e]; i0 = e; } }
    int i1 = -1; double v1 = -1e300;
    for (int e = 0; e < NEXP; e++) { if (e != i0 && acc[e] > v1) { v1 = acc[e]; i1 = e; } }
    double e1 = exp(v1 - v0);
    float g0 = (float)(1.0 / (1.0 + e1));
    float g1 = (float)(e1 / (1.0 + e1));
    top_i[t * 2] = i0; top_i[t * 2 + 1] = i1;
    gates[t * 2] = g0; gates[t * 2 + 1] = g1;
  }
}

// ---------------- capacity scan (deterministic, token-major slot order) ----------------
__global__ __launch_bounds__(256) void scan_kernel(const int* __restrict__ top_i,
                                                   const float* __restrict__ gates,
                                                   int* __restrict__ slot_pos,
                                                   float* __restrict__ keepg,
                                                   int* __restrict__ rowtok,
                                                   int* __restrict__ cnt) {
  __shared__ int hist[NEXP][256];
  int t = threadIdx.x;
  int s0 = t * 32;
  int eloc[32];
  int c[NEXP];
#pragma unroll
  for (int e = 0; e < NEXP; e++) c[e] = 0;
#pragma unroll
  for (int j = 0; j < 32; j++) { int e = top_i[s0 + j]; eloc[j] = e; c[e]++; }
#pragma unroll
  for (int e = 0; e < NEXP; e++) hist[e][t] = c[e];
  __syncthreads();
  for (int step = 1; step < 256; step <<= 1) {
    int tmp[NEXP];
#pragma unroll
    for (int e = 0; e < NEXP; e++) tmp[e] = (t >= step) ? hist[e][t - step] : 0;
    __syncthreads();
#pragma unroll
    for (int e = 0; e < NEXP; e++) hist[e][t] += tmp[e];
    __syncthreads();
  }
  int base[NEXP];
#pragma unroll
  for (int e = 0; e < NEXP; e++) base[e] = hist[e][t] - c[e];
  if (t < NEXP) {
    int tot = hist[t][255];
    cnt[t] = tot < CAP ? tot : CAP;
  }
#pragma unroll
  for (int j = 0; j < 32; j++) {
    int s = s0 + j;
    int e = eloc[j];
    int pos = base[e]++;
    bool keep = pos < CAP;
    slot_pos[s] = keep ? pos : 0;
    keepg[s] = keep ? gates[s] : 0.0f;
    if (keep) rowtok[e * CAP + pos] = s >> 1;
  }
}

// ---------------- GEMM1 + GLU ----------------
// xb: [N_TOK][DIM] bf16, w1t: [E][TWOI][DIM] bf16 (K-major), H: [E][CAP][IDIM] bf16
// 128x128 tile, async global->LDS staging, unpadded 64B-row LDS.
__global__ __launch_bounds__(256, 3) void gemm1_kernel(const unsigned short* __restrict__ xb,
                                                       const unsigned short* __restrict__ w1t,
                                                       const int* __restrict__ rowtok,
                                                       const int* __restrict__ cnt,
                                                       unsigned short* __restrict__ H) {
  int e  = blockIdx.z;
  int m0 = blockIdx.y * 128;
  int i0 = blockIdx.x * 128;
  int cnte = cnt[e];
  if (m0 >= cnte) return;

  __shared__ __align__(16) unsigned short As[128 * 32];
  __shared__ __align__(16) unsigned short Bi[128 * 32];
  __shared__ __align__(16) unsigned short Bg[128 * 32];

  int tid  = threadIdx.x;
  int lane = tid & 63;
  int wave = tid >> 6;

  // staging: wave w, instr i (i=0,1) fills LDS rows [w*32+16i, +16); lane l -> row +(l>>2), chunk (l&3)*8
  int sr0 = wave * 32 + (lane >> 2);
  int sr1 = sr0 + 16;
  int sk  = (lane & 3) * 8;

  int ma0 = m0 + sr0, ma1 = m0 + sr1;
  int tok0 = (ma0 < cnte) ? rowtok[e * CAP + ma0] : 0;
  int tok1 = (ma1 < cnte) ? rowtok[e * CAP + ma1] : 0;

  const unsigned short* w1e = w1t + (size_t)e * TWOI * DIM;
  const unsigned short* gA0  = xb + (size_t)tok0 * DIM + sk;
  const unsigned short* gA1  = xb + (size_t)tok1 * DIM + sk;
  const unsigned short* gBi0 = w1e + (size_t)(i0 + sr0) * DIM + sk;
  const unsigned short* gBi1 = w1e + (size_t)(i0 + sr1) * DIM + sk;
  const unsigned short* gBg0 = w1e + (size_t)(i0 + sr0 + IDIM) * DIM + sk;
  const unsigned short* gBg1 = w1e + (size_t)(i0 + sr1 + IDIM) * DIM + sk;

  unsigned short* lA0  = As + (wave * 2 + 0) * 512;
  unsigned short* lA1  = As + (wave * 2 + 1) * 512;
  unsigned short* lBi0 = Bi + (wave * 2 + 0) * 512;
  unsigned short* lBi1 = Bi + (wave * 2 + 1) * 512;
  unsigned short* lBg0 = Bg + (wave * 2 + 0) * 512;
  unsigned short* lBg1 = Bg + (wave * 2 + 1) * 512;

  int lane16 = lane & 15;
  int quad   = lane >> 4;
  int wm = (wave & 1) * 64;
  int wn = (wave >> 1) * 64;

  floatx4 acc_i[4][4], acc_g[4][4];
#pragma unroll
  for (int i = 0; i < 4; i++)
#pragma unroll
    for (int j = 0; j < 4; j++) {
      acc_i[i][j] = (floatx4){0.f, 0.f, 0.f, 0.f};
      acc_g[i][j] = (floatx4){0.f, 0.f, 0.f, 0.f};
    }

  for (int k0 = 0; k0 < DIM; k0 += 32) {
    __syncthreads();
    async16(gA0 + k0, lA0);
    async16(gA1 + k0, lA1);
    async16(gBi0 + k0, lBi0);
    async16(gBi1 + k0, lBi1);
    async16(gBg0 + k0, lBg0);
    async16(gBg1 + k0, lBg1);
    __syncthreads();

    short8 a[4];
#pragma unroll
    for (int i = 0; i < 4; i++)
      a[i] = *(const short8*)&As[(wm + i * 16 + lane16) * 32 + quad * 8];
#pragma unroll
    for (int j = 0; j < 4; j++) {
      short8 bi = *(const short8*)&Bi[(wn + j * 16 + lane16) * 32 + quad * 8];
#pragma unroll
      for (int i = 0; i < 4; i++)
        acc_i[i][j] = __builtin_amdgcn_mfma_f32_16x16x32_bf16(a[i], bi, acc_i[i][j], 0, 0, 0);
      short8 bg = *(const short8*)&Bg[(wn + j * 16 + lane16) * 32 + quad * 8];
#pragma unroll
      for (int i = 0; i < 4; i++)
        acc_g[i][j] = __builtin_amdgcn_mfma_f32_16x16x32_bf16(a[i], bg, acc_g[i][j], 0, 0, 0);
    }
  }

  unsigned short* He = H + (size_t)e * CAP * IDIM;
#pragma unroll
  for (int i = 0; i < 4; i++) {
#pragma unroll
    for (int r = 0; r < 4; r++) {
      int m = m0 + wm + i * 16 + quad * 4 + r;
#pragma unroll
      for (int j = 0; j < 4; j++) {
        int n = i0 + wn + j * 16 + lane16;
        float vi = acc_i[i][j][r];
        float vg = acc_g[i][j][r];
        float h = 0.5f * vi * (1.0f + erff(vi * 0.70710678118654752f)) * vg;
        He[(size_t)m * IDIM + n] = f2b(h);
      }
    }
  }
}

// ---------------- GEMM2 ----------------
// H: [E][CAP][IDIM] bf16, w2t: [E][DIM][IDIM] bf16 (K-major), expout: [E][CAP][DIM] fp32
__global__ __launch_bounds__(256, 3) void gemm2_kernel(const unsigned short* __restrict__ H,
                                                       const unsigned short* __restrict__ w2t,
                                                       const int* __restrict__ cnt,
                                                       float* __restrict__ expout) {
  int e  = blockIdx.z;
  int m0 = blockIdx.y * 128;
  int n0 = blockIdx.x * 128;
  int cnte = cnt[e];
  if (m0 >= cnte) return;

  __shared__ __align__(16) unsigned short As[128 * 32];
  __shared__ __align__(16) unsigned short Bs[128 * 32];

  int tid  = threadIdx.x;
  int lane = tid & 63;
  int wave = tid >> 6;

  int sr0 = wave * 32 + (lane >> 2);
  int sr1 = sr0 + 16;
  int sk  = (lane & 3) * 8;

  const unsigned short* He  = H + (size_t)e * CAP * IDIM;
  const unsigned short* w2e = w2t + (size_t)e * DIM * IDIM;
  const unsigned short* gA0 = He + (size_t)(m0 + sr0) * IDIM + sk;
  const unsigned short* gA1 = He + (size_t)(m0 + sr1) * IDIM + sk;
  const unsigned short* gB0 = w2e + (size_t)(n0 + sr0) * IDIM + sk;
  const unsigned short* gB1 = w2e + (size_t)(n0 + sr1) * IDIM + sk;

  unsigned short* lA0 = As + (wave * 2 + 0) * 512;
  unsigned short* lA1 = As + (wave * 2 + 1) * 512;
  unsigned short* lB0 = Bs + (wave * 2 + 0) * 512;
  unsigned short* lB1 = Bs + (wave * 2 + 1) * 512;

  int lane16 = lane & 15;
  int quad   = lane >> 4;
  int wm = (wave & 1) * 64;
  int wn = (wave >> 1) * 64;

  floatx4 acc[4][4];
#pragma unroll
  for (int i = 0; i < 4; i++)
#pragma unroll
    for (int j = 0; j < 4; j++) acc[i][j] = (floatx4){0.f, 0.f, 0.f, 0.f};

  for (int k0 = 0; k0 < IDIM; k0 += 32) {
    __syncthreads();
    async16(gA0 + k0, lA0);
    async16(gA1 + k0, lA1);
    async16(gB0 + k0, lB0);
    async16(gB1 + k0, lB1);
    __syncthreads();

    short8 a[4];
#pragma unroll
    for (int i = 0; i < 4; i++)
      a[i] = *(const short8*)&As[(wm + i * 16 + lane16) * 32 + quad * 8];
#pragma unroll
    for (int j = 0; j < 4; j++) {
      short8 b = *(const short8*)&Bs[(wn + j * 16 + lane16) * 32 + quad * 8];
#pragma unroll
      for (int i = 0; i < 4; i++)
        acc[i][j] = __builtin_amdgcn_mfma_f32_16x16x32_bf16(a[i], b, acc[i][j], 0, 0, 0);
    }
  }

  float* oute = expout + (size_t)e * CAP * DIM;
#pragma unroll
  for (int i = 0; i < 4; i++) {
#pragma unroll
    for (int r = 0; r < 4; r++) {
      int m = m0 + wm + i * 16 + quad * 4 + r;
#pragma unroll
      for (int j = 0; j < 4; j++) {
        int n = n0 + wn + j * 16 + lane16;
        oute[(size_t)m * DIM + n] = acc[i][j][r];
      }
    }
  }
}

// ---------------- combine ----------------
__global__ __launch_bounds__(256) void combine_kernel(const int* __restrict__ top_i,
                                                      const int* __restrict__ slot_pos,
                                                      const float* __restrict__ keepg,
                                                      const float* __restrict__ expout,
                                                      float* __restrict__ out) {
  int t = blockIdx.x;
  int tid = threadIdx.x;
  int e0 = top_i[t * 2], e1 = top_i[t * 2 + 1];
  int p0 = slot_pos[t * 2], p1 = slot_pos[t * 2 + 1];
  float g0 = keepg[t * 2], g1 = keepg[t * 2 + 1];
  const float4* r0 = reinterpret_cast<const float4*>(expout + ((size_t)e0 * CAP + p0) * DIM);
  const float4* r1 = reinterpret_cast<const float4*>(expout + ((size_t)e1 * CAP + p1) * DIM);
  float4 a = r0[tid], b = r1[tid];
  float4 o;
  o.x = g0 * a.x + g1 * b.x;
  o.y = g0 * a.y + g1 * b.y;
  o.z = g0 * a.z + g1 * b.z;
  o.w = g0 * a.w + g1 * b.w;
  reinterpret_cast<float4*>(out + (size_t)t * DIM)[tid] = o;
}

// ---------------- launch ----------------
extern "C" void kernel_launch(void* const* d_in, const int* in_sizes, int n_in,
                              void* d_out, int out_size, void* d_ws, size_t ws_size,
                              hipStream_t stream) {
  const float* x  = (const float*)d_in[0];
  const float* Wg = (const float*)d_in[1];
  const float* W1 = (const float*)d_in[2];
  const float* W2 = (const float*)d_in[3];
  float* out = (float*)d_out;

  char* ws = (char*)d_ws;
  size_t off = 0;
  auto alloc = [&](size_t bytes) -> void* {
    void* p = ws + off;
    off = (off + bytes + 255) & ~(size_t)255;
    return p;
  };
  int*   top_i    = (int*)alloc((size_t)N_TOK * 2 * sizeof(int));
  float* gates    = (float*)alloc((size_t)N_TOK * 2 * sizeof(float));
  int*   slot_pos = (int*)alloc((size_t)N_TOK * 2 * sizeof(int));
  float* keepg    = (float*)alloc((size_t)N_TOK * 2 * sizeof(float));
  int*   rowtok   = (int*)alloc((size_t)NEXP * CAP * sizeof(int));
  int*   cnt      = (int*)alloc((size_t)NEXP * sizeof(int));
  unsigned short* xb  = (unsigned short*)alloc((size_t)N_TOK * DIM * 2);
  unsigned short* w1t = (unsigned short*)alloc((size_t)NEXP * TWOI * DIM * 2);
  unsigned short* w2t = (unsigned short*)alloc((size_t)NEXP * DIM * IDIM * 2);
  unsigned short* Hb  = (unsigned short*)alloc((size_t)NEXP * CAP * IDIM * 2);
  float* expout = (float*)alloc((size_t)NEXP * CAP * DIM * sizeof(float));
  if (off > ws_size) return;

  hipLaunchKernelGGL(conv_x_kernel, dim3(N_TOK * DIM / 1024), dim3(256), 0, stream, x, xb);
  hipLaunchKernelGGL(transpose_kernel, dim3(TWOI / 32, DIM / 32, NEXP), dim3(256), 0, stream,
                     W1, w1t, DIM, TWOI);
  hipLaunchKernelGGL(transpose_kernel, dim3(DIM / 32, IDIM / 32, NEXP), dim3(256), 0, stream,
                     W2, w2t, IDIM, DIM);
  hipLaunchKernelGGL(router_kernel, dim3(N_TOK / 4), dim3(256), 0, stream, x, Wg, top_i, gates);
  hipLaunchKernelGGL(scan_kernel, dim3(1), dim3(256), 0, stream,
                     top_i, gates, slot_pos, keepg, rowtok, cnt);
  hipLaunchKernelGGL(gemm1_kernel, dim3(IDIM / 128, CAP / 128, NEXP), dim3(256), 0, stream,
                     xb, w1t, rowtok, cnt, Hb);
  hipLaunchKernelGGL(gemm2_kernel, dim3(DIM / 128, CAP / 128, NEXP), dim3(256), 0, stream,
                     Hb, w2t, cnt, expout);
  hipLaunchKernelGGL(combine_kernel, dim3(N_TOK), dim3(256), 0, stream,
                     top_i, slot_pos, keepg, expout, out);
}

// Round 3
// 468.775 us; speedup vs baseline: 1.2840x; 1.1513x over previous
//
#include <hip/hip_runtime.h>
#include <hip/hip_bf16.h>
#include <math.h>

#define N_TOK 4096
#define DIM   1024
#define NEXP  8
#define IDIM  2048
#define TWOI  4096
#define CAP   1280

#define W1_BLOCKS (64 * 16 * NEXP)  // 64 col-tiles x 16 row-tiles per expert
#define W2_BLOCKS (16 * 32 * NEXP)  // 16 col-tiles x 32 row-tiles per expert

using short8  = __attribute__((ext_vector_type(8))) short;
using floatx4 = __attribute__((ext_vector_type(4))) float;

__device__ __forceinline__ unsigned short f2b(float f) {
  __hip_bfloat16 h = __float2bfloat16(f);
  return *reinterpret_cast<unsigned short*>(&h);
}

// async global->LDS, 16B per lane. LDS dst = wave-uniform base + lane*16.
__device__ __forceinline__ void async16(const unsigned short* g, unsigned short* l) {
  __builtin_amdgcn_global_load_lds(
      (const __attribute__((address_space(1))) unsigned int*)g,
      (__attribute__((address_space(3))) unsigned int*)l,
      16, 0, 0);
}

// ---------------- combined weight transpose+convert ----------------
// W1: [E][DIM][TWOI] fp32 -> w1t: [E][TWOI][DIM] bf16
// W2: [E][IDIM][DIM] fp32 -> w2t: [E][DIM][IDIM] bf16
__global__ __launch_bounds__(256) void trans_kernel(const float* __restrict__ W1,
                                                    const float* __restrict__ W2,
                                                    unsigned short* __restrict__ w1t,
                                                    unsigned short* __restrict__ w2t) {
  __shared__ float tile[64][65];
  int bid = blockIdx.x;
  const float* s; unsigned short* d; int R, C, r0, c0;
  if (bid < W1_BLOCKS) {
    int e = bid >> 10;        // 1024 tiles / expert
    int t = bid & 1023;
    R = DIM; C = TWOI;
    r0 = (t & 15) * 64;
    c0 = (t >> 4) * 64;
    s = W1 + (size_t)e * R * C;
    d = w1t + (size_t)e * R * C;
  } else {
    int b2 = bid - W1_BLOCKS;
    int e = b2 >> 9;          // 512 tiles / expert
    int t = b2 & 511;
    R = IDIM; C = DIM;
    r0 = (t & 31) * 64;
    c0 = (t >> 5) * 64;
    s = W2 + (size_t)e * R * C;
    d = w2t + (size_t)e * R * C;
  }
  int tid = threadIdx.x;
  int tr = tid >> 4, tc = (tid & 15) * 4;
#pragma unroll
  for (int i = 0; i < 4; i++) {
    float4 v = *reinterpret_cast<const float4*>(&s[(size_t)(r0 + tr + i * 16) * C + c0 + tc]);
    tile[tr + i * 16][tc]     = v.x;
    tile[tr + i * 16][tc + 1] = v.y;
    tile[tr + i * 16][tc + 2] = v.z;
    tile[tr + i * 16][tc + 3] = v.w;
  }
  __syncthreads();
#pragma unroll
  for (int j = 0; j < 4; j++) {
    int c = (tid >> 4) + j * 16;
    int r4 = (tid & 15) * 4;
    ushort4 o;
    o.x = f2b(tile[r4][c]);
    o.y = f2b(tile[r4 + 1][c]);
    o.z = f2b(tile[r4 + 2][c]);
    o.w = f2b(tile[r4 + 3][c]);
    *reinterpret_cast<ushort4*>(&d[(size_t)(c0 + c) * R + r0 + r4]) = o;
  }
}

// ---------------- router (+ x->bf16 convert, + out zero-init) ----------------
__global__ __launch_bounds__(256) void router_kernel(const float* __restrict__ x,
                                                     const float* __restrict__ Wg,
                                                     unsigned short* __restrict__ xb,
                                                     float* __restrict__ out,
                                                     int* __restrict__ top_i,
                                                     float* __restrict__ gates) {
  __shared__ float wg[NEXP * DIM];
  int tid = threadIdx.x;
  for (int i = tid * 4; i < NEXP * DIM; i += 256 * 4) {
    *reinterpret_cast<float4*>(wg + i) = *reinterpret_cast<const float4*>(Wg + i);
  }
  __syncthreads();
  int wave = tid >> 6, lane = tid & 63;
  int t = blockIdx.x * 4 + wave;
  const float* xr = x + (size_t)t * DIM;
  unsigned short* xbr = xb + (size_t)t * DIM;
  float* outr = out + (size_t)t * DIM;
  double acc[NEXP];
#pragma unroll
  for (int e = 0; e < NEXP; e++) acc[e] = 0.0;
  for (int i = lane; i < DIM; i += 64) {
    float xf = xr[i];
    xbr[i] = f2b(xf);
    outr[i] = 0.0f;
    double xv = (double)xf;
#pragma unroll
    for (int e = 0; e < NEXP; e++) acc[e] += xv * (double)wg[e * DIM + i];
  }
#pragma unroll
  for (int e = 0; e < NEXP; e++) {
#pragma unroll
    for (int m = 1; m < 64; m <<= 1) acc[e] += __shfl_xor(acc[e], m, 64);
  }
  if (lane == 0) {
    int i0 = 0; double v0 = acc[0];
    for (int e = 1; e < NEXP; e++) { if (acc[e] > v0) { v0 = acc[e]; i0 = e; } }
    int i1 = -1; double v1 = -1e300;
    for (int e = 0; e < NEXP; e++) { if (e != i0 && acc[e] > v1) { v1 = acc[e]; i1 = e; } }
    double e1 = exp(v1 - v0);
    float g0 = (float)(1.0 / (1.0 + e1));
    float g1 = (float)(e1 / (1.0 + e1));
    top_i[t * 2] = i0; top_i[t * 2 + 1] = i1;
    gates[t * 2] = g0; gates[t * 2 + 1] = g1;
  }
}

// ---------------- capacity scan (deterministic, token-major slot order) ----------------
__global__ __launch_bounds__(1024) void scan_kernel(const int* __restrict__ top_i,
                                                    const float* __restrict__ gates,
                                                    int* __restrict__ rowtok,
                                                    float* __restrict__ rowgate,
                                                    int* __restrict__ cnt) {
  __shared__ int hist[NEXP][1024];
  int t = threadIdx.x;
  int s0 = t * 8;
  int eloc[8];
  int c[NEXP];
#pragma unroll
  for (int e = 0; e < NEXP; e++) c[e] = 0;
#pragma unroll
  for (int j = 0; j < 8; j++) { int e = top_i[s0 + j]; eloc[j] = e; c[e]++; }
#pragma unroll
  for (int e = 0; e < NEXP; e++) hist[e][t] = c[e];
  __syncthreads();
  for (int step = 1; step < 1024; step <<= 1) {
    int tmp[NEXP];
#pragma unroll
    for (int e = 0; e < NEXP; e++) tmp[e] = (t >= step) ? hist[e][t - step] : 0;
    __syncthreads();
#pragma unroll
    for (int e = 0; e < NEXP; e++) hist[e][t] += tmp[e];
    __syncthreads();
  }
  int base[NEXP];
#pragma unroll
  for (int e = 0; e < NEXP; e++) base[e] = hist[e][t] - c[e];
  if (t < NEXP) {
    int tot = hist[t][1023];
    cnt[t] = tot < CAP ? tot : CAP;
  }
#pragma unroll
  for (int j = 0; j < 8; j++) {
    int s = s0 + j;
    int e = eloc[j];
    int pos = base[e]++;
    if (pos < CAP) {
      rowtok[e * CAP + pos] = s >> 1;
      rowgate[e * CAP + pos] = gates[s];
    }
  }
}

// ---------------- GEMM1 + GLU ----------------
// Block tile: 128 m x 64 n of H (both inp & gate halves). Per-wave 64x32 dual acc = 64 regs.
__global__ __launch_bounds__(256, 3) void gemm1_kernel(const unsigned short* __restrict__ xb,
                                                       const unsigned short* __restrict__ w1t,
                                                       const int* __restrict__ rowtok,
                                                       const int* __restrict__ cnt,
                                                       unsigned short* __restrict__ H) {
  int e  = blockIdx.z;
  int m0 = blockIdx.y * 128;
  int i0 = blockIdx.x * 64;
  int cnte = cnt[e];
  if (m0 >= cnte) return;

  __shared__ __align__(16) unsigned short As[128 * 32];
  __shared__ __align__(16) unsigned short Bi[64 * 32];
  __shared__ __align__(16) unsigned short Bg[64 * 32];

  int tid  = threadIdx.x;
  int lane = tid & 63;
  int wave = tid >> 6;

  int srA0 = wave * 32 + (lane >> 2);
  int srA1 = srA0 + 16;
  int srB  = wave * 16 + (lane >> 2);
  int sk   = (lane & 3) * 8;

  int ma0 = m0 + srA0, ma1 = m0 + srA1;
  int tok0 = (ma0 < cnte) ? rowtok[e * CAP + ma0] : 0;
  int tok1 = (ma1 < cnte) ? rowtok[e * CAP + ma1] : 0;

  const unsigned short* w1e = w1t + (size_t)e * TWOI * DIM;
  const unsigned short* gA0 = xb + (size_t)tok0 * DIM + sk;
  const unsigned short* gA1 = xb + (size_t)tok1 * DIM + sk;
  const unsigned short* gBi = w1e + (size_t)(i0 + srB) * DIM + sk;
  const unsigned short* gBg = w1e + (size_t)(i0 + srB + IDIM) * DIM + sk;

  unsigned short* lA0 = As + (wave * 2 + 0) * 512;
  unsigned short* lA1 = As + (wave * 2 + 1) * 512;
  unsigned short* lBi = Bi + wave * 512;
  unsigned short* lBg = Bg + wave * 512;

  int lane16 = lane & 15;
  int quad   = lane >> 4;
  int wm = (wave & 1) * 64;
  int wn = (wave >> 1) * 32;

  floatx4 acc_i[4][2], acc_g[4][2];
#pragma unroll
  for (int i = 0; i < 4; i++)
#pragma unroll
    for (int j = 0; j < 2; j++) {
      acc_i[i][j] = (floatx4){0.f, 0.f, 0.f, 0.f};
      acc_g[i][j] = (floatx4){0.f, 0.f, 0.f, 0.f};
    }

  for (int k0 = 0; k0 < DIM; k0 += 32) {
    __syncthreads();
    async16(gA0 + k0, lA0);
    async16(gA1 + k0, lA1);
    async16(gBi + k0, lBi);
    async16(gBg + k0, lBg);
    __syncthreads();

    short8 a[4];
#pragma unroll
    for (int i = 0; i < 4; i++)
      a[i] = *(const short8*)&As[(wm + i * 16 + lane16) * 32 + quad * 8];
#pragma unroll
    for (int j = 0; j < 2; j++) {
      short8 bi = *(const short8*)&Bi[(wn + j * 16 + lane16) * 32 + quad * 8];
#pragma unroll
      for (int i = 0; i < 4; i++)
        acc_i[i][j] = __builtin_amdgcn_mfma_f32_16x16x32_bf16(a[i], bi, acc_i[i][j], 0, 0, 0);
      short8 bg = *(const short8*)&Bg[(wn + j * 16 + lane16) * 32 + quad * 8];
#pragma unroll
      for (int i = 0; i < 4; i++)
        acc_g[i][j] = __builtin_amdgcn_mfma_f32_16x16x32_bf16(a[i], bg, acc_g[i][j], 0, 0, 0);
    }
  }

  unsigned short* He = H + (size_t)e * CAP * IDIM;
#pragma unroll
  for (int i = 0; i < 4; i++) {
#pragma unroll
    for (int r = 0; r < 4; r++) {
      int m = m0 + wm + i * 16 + quad * 4 + r;
#pragma unroll
      for (int j = 0; j < 2; j++) {
        int n = i0 + wn + j * 16 + lane16;
        float vi = acc_i[i][j][r];
        float vg = acc_g[i][j][r];
        float h = 0.5f * vi * (1.0f + erff(vi * 0.70710678118654752f)) * vg;
        He[(size_t)m * IDIM + n] = f2b(h);
      }
    }
  }
}

// ---------------- GEMM2 + scatter-combine ----------------
// H: [E][CAP][IDIM] bf16, w2t: [E][DIM][IDIM] bf16 (K-major).
// Epilogue scatters gate-weighted rows directly into out via atomicAdd
// (<=2 contributions per element; fp32 add is commutative -> deterministic).
__global__ __launch_bounds__(256, 3) void gemm2_kernel(const unsigned short* __restrict__ H,
                                                       const unsigned short* __restrict__ w2t,
                                                       const int* __restrict__ cnt,
                                                       const int* __restrict__ rowtok,
                                                       const float* __restrict__ rowgate,
                                                       float* __restrict__ out) {
  int e  = blockIdx.z;
  int m0 = blockIdx.y * 128;
  int n0 = blockIdx.x * 128;
  int cnte = cnt[e];
  if (m0 >= cnte) return;

  __shared__ __align__(16) unsigned short As[128 * 32];
  __shared__ __align__(16) unsigned short Bs[128 * 32];

  int tid  = threadIdx.x;
  int lane = tid & 63;
  int wave = tid >> 6;

  int sr0 = wave * 32 + (lane >> 2);
  int sr1 = sr0 + 16;
  int sk  = (lane & 3) * 8;

  const unsigned short* He  = H + (size_t)e * CAP * IDIM;
  const unsigned short* w2e = w2t + (size_t)e * DIM * IDIM;
  const unsigned short* gA0 = He + (size_t)(m0 + sr0) * IDIM + sk;
  const unsigned short* gA1 = He + (size_t)(m0 + sr1) * IDIM + sk;
  const unsigned short* gB0 = w2e + (size_t)(n0 + sr0) * IDIM + sk;
  const unsigned short* gB1 = w2e + (size_t)(n0 + sr1) * IDIM + sk;

  unsigned short* lA0 = As + (wave * 2 + 0) * 512;
  unsigned short* lA1 = As + (wave * 2 + 1) * 512;
  unsigned short* lB0 = Bs + (wave * 2 + 0) * 512;
  unsigned short* lB1 = Bs + (wave * 2 + 1) * 512;

  int lane16 = lane & 15;
  int quad   = lane >> 4;
  int wm = (wave & 1) * 64;
  int wn = (wave >> 1) * 64;

  floatx4 acc[4][4];
#pragma unroll
  for (int i = 0; i < 4; i++)
#pragma unroll
    for (int j = 0; j < 4; j++) acc[i][j] = (floatx4){0.f, 0.f, 0.f, 0.f};

  for (int k0 = 0; k0 < IDIM; k0 += 32) {
    __syncthreads();
    async16(gA0 + k0, lA0);
    async16(gA1 + k0, lA1);
    async16(gB0 + k0, lB0);
    async16(gB1 + k0, lB1);
    __syncthreads();

    short8 a[4];
#pragma unroll
    for (int i = 0; i < 4; i++)
      a[i] = *(const short8*)&As[(wm + i * 16 + lane16) * 32 + quad * 8];
#pragma unroll
    for (int j = 0; j < 4; j++) {
      short8 b = *(const short8*)&Bs[(wn + j * 16 + lane16) * 32 + quad * 8];
#pragma unroll
      for (int i = 0; i < 4; i++)
        acc[i][j] = __builtin_amdgcn_mfma_f32_16x16x32_bf16(a[i], b, acc[i][j], 0, 0, 0);
    }
  }

#pragma unroll
  for (int i = 0; i < 4; i++) {
#pragma unroll
    for (int r = 0; r < 4; r++) {
      int m = m0 + wm + i * 16 + quad * 4 + r;
      if (m < cnte) {
        int tok = rowtok[e * CAP + m];
        float g = rowgate[e * CAP + m];
        float* orow = out + (size_t)tok * DIM;
#pragma unroll
        for (int j = 0; j < 4; j++) {
          int n = n0 + wn + j * 16 + lane16;
          atomicAdd(orow + n, g * acc[i][j][r]);
        }
      }
    }
  }
}

// ---------------- launch ----------------
extern "C" void kernel_launch(void* const* d_in, const int* in_sizes, int n_in,
                              void* d_out, int out_size, void* d_ws, size_t ws_size,
                              hipStream_t stream) {
  const float* x  = (const float*)d_in[0];
  const float* Wg = (const float*)d_in[1];
  const float* W1 = (const float*)d_in[2];
  const float* W2 = (const float*)d_in[3];
  float* out = (float*)d_out;

  char* ws = (char*)d_ws;
  size_t off = 0;
  auto alloc = [&](size_t bytes) -> void* {
    void* p = ws + off;
    off = (off + bytes + 255) & ~(size_t)255;
    return p;
  };
  int*   top_i   = (int*)alloc((size_t)N_TOK * 2 * sizeof(int));
  float* gates   = (float*)alloc((size_t)N_TOK * 2 * sizeof(float));
  int*   rowtok  = (int*)alloc((size_t)NEXP * CAP * sizeof(int));
  float* rowgate = (float*)alloc((size_t)NEXP * CAP * sizeof(float));
  int*   cnt     = (int*)alloc((size_t)NEXP * sizeof(int));
  unsigned short* xb  = (unsigned short*)alloc((size_t)N_TOK * DIM * 2);
  unsigned short* w1t = (unsigned short*)alloc((size_t)NEXP * TWOI * DIM * 2);
  unsigned short* w2t = (unsigned short*)alloc((size_t)NEXP * DIM * IDIM * 2);
  unsigned short* Hb  = (unsigned short*)alloc((size_t)NEXP * CAP * IDIM * 2);
  if (off > ws_size) return;

  hipLaunchKernelGGL(trans_kernel, dim3(W1_BLOCKS + W2_BLOCKS), dim3(256), 0, stream,
                     W1, W2, w1t, w2t);
  hipLaunchKernelGGL(router_kernel, dim3(N_TOK / 4), dim3(256), 0, stream,
                     x, Wg, xb, out, top_i, gates);
  hipLaunchKernelGGL(scan_kernel, dim3(1), dim3(1024), 0, stream,
                     top_i, gates, rowtok, rowgate, cnt);
  hipLaunchKernelGGL(gemm1_kernel, dim3(IDIM / 64, CAP / 128, NEXP), dim3(256), 0, stream,
                     xb, w1t, rowtok, cnt, Hb);
  hipLaunchKernelGGL(gemm2_kernel, dim3(DIM / 128, CAP / 128, NEXP), dim3(256), 0, stream,
                     Hb, w2t, cnt, rowtok, rowgate, out);
}